// Round 3
// baseline (261.534 us; speedup 1.0000x reference)
//
#include <hip/hip_runtime.h>
#include <hip/hip_fp16.h>
#include <math.h>

#define V_   6890
#define FC_  13776
#define N_   2
#define H_   336
#define W_   336
#define K_   28
#define NPIX (N_*H_*W_)

#define SIGMA_INV 1.0e4f
#define GAMMA_INV 1.0e4f
#define EPS_      1e-10f
#define ZFAR_     100.0f
#define ZSCALE    (1.0f/99.0f)
#define LOG2E     1.442695041f

// fast single-instruction transcendentals (precision slack: threshold 0.24, current absmax 0.004)
static __device__ __forceinline__ float fexp(float x)  { return __builtin_amdgcn_exp2f(x * LOG2E); }
static __device__ __forceinline__ float frcp(float x)  { return __builtin_amdgcn_rcpf(x); }
static __device__ __forceinline__ float frsq(float x)  { return __builtin_amdgcn_rsqf(x); }

// ws layout: [0, 3*V floats) vertex-normal accumulator (fp32, atomics);
// then fp16 face table, 32 halfs (64 B) per face:
//   halfs 0..8  : p0,p1,p2      (face_pass1)
//   halfs 9..17 : c0,c1,c2      (face_pass1)
//   halfs 18..26: n0,n1,n2      (face_pass2)
#define FD_OFFSET 82944   // align_up(3*6890*4, 256)

__global__ __launch_bounds__(256)
void face_pass1(const float* __restrict__ verts,
                const float* __restrict__ vcol,
                const int*   __restrict__ faces,
                float* __restrict__ vnAcc,
                __half2* __restrict__ fd) {
    int i = blockIdx.x * blockDim.x + threadIdx.x;
    if (i >= FC_) return;
    int f0 = faces[i*3+0], f1 = faces[i*3+1], f2 = faces[i*3+2];
    float a[18];
    a[0] = verts[f0*3+0]; a[1] = verts[f0*3+1]; a[2] = verts[f0*3+2];
    a[3] = verts[f1*3+0]; a[4] = verts[f1*3+1]; a[5] = verts[f1*3+2];
    a[6] = verts[f2*3+0]; a[7] = verts[f2*3+1]; a[8] = verts[f2*3+2];
    float e1x = a[3]-a[0], e1y = a[4]-a[1], e1z = a[5]-a[2];
    float e2x = a[6]-a[0], e2y = a[7]-a[1], e2z = a[8]-a[2];
    float fnx = e1y*e2z - e1z*e2y;
    float fny = e1z*e2x - e1x*e2z;
    float fnz = e1x*e2y - e1y*e2x;
    atomicAdd(&vnAcc[f0*3+0], fnx); atomicAdd(&vnAcc[f0*3+1], fny); atomicAdd(&vnAcc[f0*3+2], fnz);
    atomicAdd(&vnAcc[f1*3+0], fnx); atomicAdd(&vnAcc[f1*3+1], fny); atomicAdd(&vnAcc[f1*3+2], fnz);
    atomicAdd(&vnAcc[f2*3+0], fnx); atomicAdd(&vnAcc[f2*3+1], fny); atomicAdd(&vnAcc[f2*3+2], fnz);
    a[9]  = vcol[f0*3+0]; a[10] = vcol[f0*3+1]; a[11] = vcol[f0*3+2];
    a[12] = vcol[f1*3+0]; a[13] = vcol[f1*3+1]; a[14] = vcol[f1*3+2];
    a[15] = vcol[f2*3+0]; a[16] = vcol[f2*3+1]; a[17] = vcol[f2*3+2];
    __half2* o = fd + (size_t)i * 16;
    #pragma unroll
    for (int t = 0; t < 9; ++t) o[t] = __floats2half2_rn(a[2*t], a[2*t+1]);
}

__global__ __launch_bounds__(256)
void face_pass2(const int* __restrict__ faces,
                const float* __restrict__ vn,
                __half2* __restrict__ fd) {
    int i = blockIdx.x * blockDim.x + threadIdx.x;
    if (i >= FC_) return;
    int fidx[3] = { faces[i*3+0], faces[i*3+1], faces[i*3+2] };
    float b[10];
    #pragma unroll
    for (int v = 0; v < 3; ++v) {
        float x = vn[fidx[v]*3+0], y = vn[fidx[v]*3+1], z = vn[fidx[v]*3+2];
        float inv = frsq(fmaxf(x*x + y*y + z*z, 1e-12f));
        b[v*3+0] = x*inv; b[v*3+1] = y*inv; b[v*3+2] = z*inv;
    }
    b[9] = 0.0f;
    __half2* o = fd + (size_t)i * 16 + 9;
    #pragma unroll
    for (int t = 0; t < 5; ++t) o[t] = __floats2half2_rn(b[2*t], b[2*t+1]);
}

__global__ __launch_bounds__(256)
void pixel_kernel(const int*   __restrict__ ptf,
                  const float* __restrict__ bary,
                  const float* __restrict__ dists,
                  const float* __restrict__ zbuf,
                  const ushort* __restrict__ fd16,
                  const float* __restrict__ light,
                  const float* __restrict__ amb,
                  const float* __restrict__ dif,
                  const float* __restrict__ spec,
                  const float* __restrict__ cam,
                  float* __restrict__ out) {
    int tid = blockIdx.x * blockDim.x + threadIdx.x;
    int pix = tid >> 5;        // 32 lanes per pixel
    int j   = tid & 31;        // lane-in-pixel; j<28 active
    if (pix >= NPIX) return;

    bool act = (j < K_);
    size_t sbase = (size_t)pix * K_ + j;

    int pf = -1;
    float d = 0.0f, z = 0.0f, w0 = 0.0f, w1 = 0.0f, w2 = 0.0f;
    if (act) {
        pf = ptf[sbase];
        d  = dists[sbase];
        z  = zbuf[sbase];
        w0 = bary[sbase*3+0];
        w1 = bary[sbase*3+1];
        w2 = bary[sbase*3+2];
        out[(size_t)NPIX*4 + sbase] = z;   // zbuf passthrough
    }

    float zi = 0.0f, prob = 0.0f, cr = 0.0f, cg = 0.0f, cb = 0.0f;
    if (pf >= 0) {
        prob = frcp(1.0f + fexp(d * SIGMA_INV));   // sigmoid(-d/sigma)
        zi   = (ZFAR_ - z) * ZSCALE;

        const uint4* fq = (const uint4*)(fd16 + (size_t)pf * 32);
        union { uint4 u[4]; __half h[32]; } F;
        F.u[0] = fq[0]; F.u[1] = fq[1]; F.u[2] = fq[2]; F.u[3] = fq[3];

        float p0x = __half2float(F.h[0]),  p0y = __half2float(F.h[1]),  p0z = __half2float(F.h[2]);
        float p1x = __half2float(F.h[3]),  p1y = __half2float(F.h[4]),  p1z = __half2float(F.h[5]);
        float p2x = __half2float(F.h[6]),  p2y = __half2float(F.h[7]),  p2z = __half2float(F.h[8]);
        float c0x = __half2float(F.h[9]),  c0y = __half2float(F.h[10]), c0z = __half2float(F.h[11]);
        float c1x = __half2float(F.h[12]), c1y = __half2float(F.h[13]), c1z = __half2float(F.h[14]);
        float c2x = __half2float(F.h[15]), c2y = __half2float(F.h[16]), c2z = __half2float(F.h[17]);
        float n0x = __half2float(F.h[18]), n0y = __half2float(F.h[19]), n0z = __half2float(F.h[20]);
        float n1x = __half2float(F.h[21]), n1y = __half2float(F.h[22]), n1z = __half2float(F.h[23]);
        float n2x = __half2float(F.h[24]), n2y = __half2float(F.h[25]), n2z = __half2float(F.h[26]);

        float px = w0*p0x + w1*p1x + w2*p2x;
        float py = w0*p0y + w1*p1y + w2*p2y;
        float pz = w0*p0z + w1*p1z + w2*p2z;
        float nux = w0*n0x + w1*n1x + w2*n2x;
        float nuy = w0*n0y + w1*n1y + w2*n2y;
        float nuz = w0*n0z + w1*n1z + w2*n2z;
        float ninv = frsq(fmaxf(nux*nux + nuy*nuy + nuz*nuz, 1e-12f));
        float nx = nux*ninv, ny = nuy*ninv, nz = nuz*ninv;
        float tr = w0*c0x + w1*c1x + w2*c2x;
        float tg = w0*c0y + w1*c1y + w2*c2y;
        float tb = w0*c0z + w1*c1z + w2*c2z;

        float lvx = light[0] - px, lvy = light[1] - py, lvz = light[2] - pz;
        float linv = frsq(fmaxf(lvx*lvx + lvy*lvy + lvz*lvz, 1e-12f));
        lvx *= linv; lvy *= linv; lvz *= linv;
        float ldn = lvx*nx + lvy*ny + lvz*nz;
        float ndotl = fmaxf(ldn, 0.0f);

        float vvx = cam[0] - px, vvy = cam[1] - py, vvz = cam[2] - pz;
        float vinv = frsq(fmaxf(vvx*vvx + vvy*vvy + vvz*vvz, 1e-12f));
        vvx *= vinv; vvy *= vinv; vvz *= vinv;

        float rx = 2.0f*ldn*nx - lvx;
        float ry = 2.0f*ldn*ny - lvy;
        float rz = 2.0f*ldn*nz - lvz;
        float ca = fmaxf(rx*vvx + ry*vvy + rz*vvz, 0.0f);
        float p64 = ca*ca; p64 *= p64; p64 *= p64; p64 *= p64; p64 *= p64; p64 *= p64;

        cr = (amb[0] + dif[0]*ndotl)*tr + spec[0]*p64;
        cg = (amb[1] + dif[1]*ndotl)*tg + spec[1]*p64;
        cb = (amb[2] + dif[2]*ndotl)*tb + spec[2]*p64;
    }

    // ---- subgroup (32-lane) reductions: exact two-pass softmax-style blend
    float m = fmaxf(zi, EPS_);
    #pragma unroll
    for (int o = 16; o; o >>= 1) m = fmaxf(m, __shfl_xor(m, o, 32));

    float w = prob * fexp((zi - m) * GAMMA_INV);   // underflows to 0 safely
    float swr = w * cr, swg = w * cg, swb = w * cb;
    float om  = 1.0f - prob;
    #pragma unroll
    for (int o = 16; o; o >>= 1) {
        w   += __shfl_xor(w,   o, 32);
        swr += __shfl_xor(swr, o, 32);
        swg += __shfl_xor(swg, o, 32);
        swb += __shfl_xor(swb, o, 32);
        om  *= __shfl_xor(om,  o, 32);
    }

    if (j == 0) {
        float deltaw = fexp((EPS_ - m) * GAMMA_INV);
        float inv = frcp(w + deltaw);
        float4 img;
        img.x = (swr + deltaw) * inv;   // BG = 1
        img.y = (swg + deltaw) * inv;
        img.z = (swb + deltaw) * inv;
        img.w = 1.0f - om;
        ((float4*)out)[pix] = img;
    }
}

extern "C" void kernel_launch(void* const* d_in, const int* in_sizes, int n_in,
                              void* d_out, int out_size, void* d_ws, size_t ws_size,
                              hipStream_t stream) {
    const float* verts = (const float*)d_in[0];
    const float* vcol  = (const float*)d_in[1];
    const int*   faces = (const int*)d_in[2];
    const int*   ptf   = (const int*)d_in[3];
    const float* bary  = (const float*)d_in[4];
    const float* dists = (const float*)d_in[5];
    const float* zbuf  = (const float*)d_in[6];
    const float* light = (const float*)d_in[7];
    const float* amb   = (const float*)d_in[8];
    const float* dif   = (const float*)d_in[9];
    const float* spec  = (const float*)d_in[10];
    const float* cam   = (const float*)d_in[11];
    float* out = (float*)d_out;

    float*   vnAcc = (float*)d_ws;
    __half2* fdat  = (__half2*)((char*)d_ws + FD_OFFSET);

    hipMemsetAsync(vnAcc, 0, (size_t)V_ * 3 * sizeof(float), stream);
    face_pass1<<<(FC_ + 255)/256, 256, 0, stream>>>(verts, vcol, faces, vnAcc, fdat);
    face_pass2<<<(FC_ + 255)/256, 256, 0, stream>>>(faces, vnAcc, fdat);

    int blocks = (NPIX * 32 + 255) / 256;
    pixel_kernel<<<blocks, 256, 0, stream>>>(
        ptf, bary, dists, zbuf, (const ushort*)fdat,
        light, amb, dif, spec, cam, out);
}